// Round 7
// baseline (210.185 us; speedup 1.0000x reference)
//
#include <hip/hip_runtime.h>
#include <hip/hip_bf16.h>
#include <math.h>

#define BATCH 2
#define SEQ   2048
#define HID   1024
#define NH    16
#define HD    64
#define MROWS (BATCH * SEQ)   // 4096
#define VSTR  4160            // padded row stride of V' (avoid 8192B channel camping)

typedef unsigned short u16;
typedef short bf16x8 __attribute__((ext_vector_type(8)));
typedef float f32x4  __attribute__((ext_vector_type(4)));

#define LOG2E 1.4426950408889634f
#define C2    (0.125f * LOG2E)      // score scale folded into log2 domain
#define M2F   23.083120f            // fixed softmax shift (shift-invariant)

static __device__ __forceinline__ u16 f2bf(float f) {
    union { float f; unsigned int u; } v; v.f = f;
    unsigned int r = (v.u + 0x7FFF + ((v.u >> 16) & 1)) >> 16;  // RNE
    return (u16)r;
}

static __device__ __forceinline__ unsigned int pk_bf16(float a, float b) {
    union { __hip_bfloat162 h; unsigned int u; } r;
    float2 f; f.x = a; f.y = b;
    r.h = __float22bfloat162_rn(f);   // packed cvt where HW supports it
    return r.u;
}

static __device__ __forceinline__ f32x4 mfma16(bf16x8 a, bf16x8 b, f32x4 c) {
    return __builtin_amdgcn_mfma_f32_16x16x32_bf16(a, b, c, 0, 0, 0);
}

// global -> LDS async copy, 16 B per lane; LDS dest = wave-uniform base + lane*16.
static __device__ __forceinline__ void ldsload16(const void* g, void* l) {
    __builtin_amdgcn_global_load_lds(
        (const __attribute__((address_space(1))) void*)(unsigned long long)(uintptr_t)g,
        (__attribute__((address_space(3))) void*)(unsigned int)(uintptr_t)l,
        16, 0, 0);
}

// ---------------------------------------------------------------------------
// Fused prep: [0,4096) weight cast; [4096,8192) LayerNorm; [8192,8196) mask2
// precompute: mask2[s] = -1000*(1-mask)*LOG2E - M2F.
// ---------------------------------------------------------------------------
__global__ __launch_bounds__(256) void prep_kernel(const float* __restrict__ x,
                                                   const float* __restrict__ gamma,
                                                   const float* __restrict__ beta,
                                                   u16* __restrict__ h,
                                                   const float* __restrict__ w0,
                                                   const float* __restrict__ w1,
                                                   const float* __restrict__ w2,
                                                   const float* __restrict__ w3,
                                                   u16* o0, u16* o1, u16* o2, u16* o3,
                                                   const float* __restrict__ maskg,
                                                   float* __restrict__ m2g)
{
    __shared__ float red[8];
    const int t = threadIdx.x;
    if (blockIdx.x >= 8192) {
        const int idx = ((blockIdx.x - 8192) * 256 + t) * 4;
        const float4 m = *(const float4*)(maskg + idx);
        float4 o;
        o.x = fmaf(-1000.0f * (1.0f - m.x), LOG2E, -M2F);
        o.y = fmaf(-1000.0f * (1.0f - m.y), LOG2E, -M2F);
        o.z = fmaf(-1000.0f * (1.0f - m.z), LOG2E, -M2F);
        o.w = fmaf(-1000.0f * (1.0f - m.w), LOG2E, -M2F);
        *(float4*)(m2g + idx) = o;
        return;
    }
    if (blockIdx.x < 4096) {
        const int blk = blockIdx.x;
        const int which = blk >> 10;
        const int lb = blk & 1023;
        const float* src = which == 0 ? w0 : which == 1 ? w1 : which == 2 ? w2 : w3;
        u16* dst = which == 0 ? o0 : which == 1 ? o1 : which == 2 ? o2 : o3;
        const int idx = (lb * 256 + t) * 4;
        const float4 f = *(const float4*)(src + idx);
        union { u16 s[4]; uint2 v; } p;
        p.s[0] = f2bf(f.x); p.s[1] = f2bf(f.y); p.s[2] = f2bf(f.z); p.s[3] = f2bf(f.w);
        *(uint2*)(dst + idx) = p.v;
        return;
    }
    const int row = blockIdx.x - 4096;
    const float4 xv = ((const float4*)(x + (size_t)row * HID))[t];
    float s  = xv.x + xv.y + xv.z + xv.w;
    float ss = xv.x * xv.x + xv.y * xv.y + xv.z * xv.z + xv.w * xv.w;
#pragma unroll
    for (int off = 32; off > 0; off >>= 1) {
        s  += __shfl_down(s, off);
        ss += __shfl_down(ss, off);
    }
    const int wid = t >> 6;
    if ((t & 63) == 0) { red[wid] = s; red[4 + wid] = ss; }
    __syncthreads();
    s  = red[0] + red[1] + red[2] + red[3];
    ss = red[4] + red[5] + red[6] + red[7];
    const float mu   = s * (1.0f / HID);
    const float var  = ss * (1.0f / HID) - mu * mu;
    const float rstd = rsqrtf(var + 1e-12f);
    const float4 g  = ((const float4*)gamma)[t];
    const float4 bb = ((const float4*)beta)[t];
    union { u16 s[4]; uint2 v; } p;
    p.s[0] = f2bf((xv.x - mu) * rstd * g.x + bb.x);
    p.s[1] = f2bf((xv.y - mu) * rstd * g.y + bb.y);
    p.s[2] = f2bf((xv.z - mu) * rstd * g.z + bb.z);
    p.s[3] = f2bf((xv.w - mu) * rstd * g.w + bb.w);
    ((uint2*)(h + (size_t)row * HID))[t] = p.v;
}

// ---------------------------------------------------------------------------
// MFMA GEMM core, double-buffered: 128x128 tile, BK=32, 4 waves 2x2, wave=64x64.
// A[M,K], B[N,K] row-major bf16 (C = A * B^T).  As/Bs are 8192-u16 (2 buffers).
// ---------------------------------------------------------------------------
static __device__ __forceinline__ void gemm_core(const u16* __restrict__ A,
                                                 const u16* __restrict__ B,
                                                 int K, int bm, int bn,
                                                 u16* As, u16* Bs,
                                                 int wave, int lane,
                                                 f32x4 acc[4][4])
{
    const int l15  = lane & 15;
    const int quad = lane >> 4;
    const int wm = (wave >> 1) * 64;
    const int wn = (wave & 1) * 64;

    const int c1 = wave * 64 + lane;
    const int c2 = c1 + 256;
    const u16* A1 = A + (size_t)(bm + (c1 >> 2)) * K + (c1 & 3) * 8;
    const u16* A2 = A + (size_t)(bm + (c2 >> 2)) * K + (c2 & 3) * 8;
    const u16* B1 = B + (size_t)(bn + (c1 >> 2)) * K + (c1 & 3) * 8;
    const u16* B2 = B + (size_t)(bn + (c2 >> 2)) * K + (c2 & 3) * 8;
    const int o1 = wave * 512;
    const int o2 = 2048 + wave * 512;

    // stage K-step 0 into buffer 0
    ldsload16(A1, As + o1);
    ldsload16(A2, As + o2);
    ldsload16(B1, Bs + o1);
    ldsload16(B2, Bs + o2);

    const int nstep = K >> 5;
    for (int i = 0; i < nstep; i++) {
        __syncthreads();                      // drains step-i loads (vmcnt 0)
        const int cb = (i & 1) * 4096;
        if (i + 1 < nstep) {
            const int nb = ((i + 1) & 1) * 4096;
            const int k0 = (i + 1) * 32;
            ldsload16(A1 + k0, As + nb + o1);
            ldsload16(A2 + k0, As + nb + o2);
            ldsload16(B1 + k0, Bs + nb + o1);
            ldsload16(B2 + k0, Bs + nb + o2);
        }
        bf16x8 af[4], bfr[4];
#pragma unroll
        for (int mt = 0; mt < 4; mt++)
            af[mt] = *(const bf16x8*)&As[cb + (wm + mt * 16 + l15) * 32 + quad * 8];
#pragma unroll
        for (int nt = 0; nt < 4; nt++)
            bfr[nt] = *(const bf16x8*)&Bs[cb + (wn + nt * 16 + l15) * 32 + quad * 8];
#pragma unroll
        for (int mt = 0; mt < 4; mt++)
#pragma unroll
            for (int nt = 0; nt < 4; nt++)
                acc[mt][nt] = mfma16(af[mt], bfr[nt], acc[mt][nt]);
    }
}

// ---------------------------------------------------------------------------
// Fused QKV.  Blocks 0..255: q.  256..511: k.  512..767: V' = Wv*h^T (VSTR).
// ---------------------------------------------------------------------------
__global__ __launch_bounds__(256) void qkv_gemm(const u16* __restrict__ h,
                                                const u16* __restrict__ wq,
                                                const u16* __restrict__ wk,
                                                const u16* __restrict__ wv,
                                                const float* __restrict__ bq,
                                                const float* __restrict__ bk,
                                                const float* __restrict__ bv,
                                                u16* __restrict__ qo,
                                                u16* __restrict__ ko,
                                                u16* __restrict__ vo)
{
    __shared__ u16 As[8192];
    __shared__ u16 Bs[8192];
    const int blk  = blockIdx.x;
    const int wave = threadIdx.x >> 6;
    const int lane = threadIdx.x & 63;
    const int l15  = lane & 15;
    const int quad = lane >> 4;
    const int wm = (wave >> 1) * 64;
    const int wn = (wave & 1) * 64;

    f32x4 acc[4][4];
#pragma unroll
    for (int mt = 0; mt < 4; mt++)
#pragma unroll
        for (int nt = 0; nt < 4; nt++) acc[mt][nt] = (f32x4)0.0f;

    if (blk < 512) {
        const u16* W     = (blk < 256) ? wq : wk;
        const float* bia = (blk < 256) ? bq : bk;
        u16* out         = (blk < 256) ? qo : ko;
        const int local = blk & 255;
        const int bm = (local >> 3) * 128;
        const int bn = (local & 7) * 128;
        gemm_core(h, W, HID, bm, bn, As, Bs, wave, lane, acc);

        float bv4[4];
#pragma unroll
        for (int nt = 0; nt < 4; nt++) bv4[nt] = bia[bn + wn + nt * 16 + l15];
#pragma unroll
        for (int mt = 0; mt < 4; mt++)
#pragma unroll
            for (int r = 0; r < 4; r++) {
                const int m  = bm + wm + mt * 16 + quad * 4 + r;
                const int bI = m >> 11;
                const int sI = m & (SEQ - 1);
#pragma unroll
                for (int nt = 0; nt < 4; nt++) {
                    const int n  = bn + wn + nt * 16 + l15;
                    const int hh = n >> 6;
                    const int d  = n & 63;
                    out[(((size_t)(bI * NH + hh) * SEQ + sI) << 6) + d] =
                        f2bf(acc[mt][nt][r] + bv4[nt]);
                }
            }
    } else {
        const int local = blk - 512;
        const int bm = (local & 7) * 128;
        const int bn = (local >> 3) * 128;
        gemm_core(wv, h, HID, bm, bn, As, Bs, wave, lane, acc);

#pragma unroll
        for (int mt = 0; mt < 4; mt++) {
            const f32x4 bm4 = *(const f32x4*)&bv[bm + wm + mt * 16 + quad * 4];
#pragma unroll
            for (int r = 0; r < 4; r++) {
                const int row = bm + wm + mt * 16 + quad * 4 + r;
#pragma unroll
                for (int nt = 0; nt < 4; nt++) {
                    const int col = bn + wn + nt * 16 + l15;
                    vo[(size_t)row * VSTR + col] = f2bf(acc[mt][nt][r] + bm4[r]);
                }
            }
        }
    }
}

// ---------------------------------------------------------------------------
// Output projection: out = ctx * Wd^T + bd, fp32 out.
// ---------------------------------------------------------------------------
__global__ __launch_bounds__(256) void out_gemm(const u16* __restrict__ ctx,
                                                const u16* __restrict__ wd,
                                                const float* __restrict__ bd,
                                                float* __restrict__ out)
{
    __shared__ u16 As[8192];
    __shared__ u16 Bs[8192];
    const int blk  = blockIdx.x;
    const int wave = threadIdx.x >> 6;
    const int lane = threadIdx.x & 63;
    const int l15  = lane & 15;
    const int quad = lane >> 4;
    const int wm = (wave >> 1) * 64;
    const int wn = (wave & 1) * 64;
    const int bm = (blk >> 3) * 128;
    const int bn = (blk & 7) * 128;

    f32x4 acc[4][4];
#pragma unroll
    for (int mt = 0; mt < 4; mt++)
#pragma unroll
        for (int nt = 0; nt < 4; nt++) acc[mt][nt] = (f32x4)0.0f;

    gemm_core(ctx, wd, HID, bm, bn, As, Bs, wave, lane, acc);

    float bv4[4];
#pragma unroll
    for (int nt = 0; nt < 4; nt++) bv4[nt] = bd[bn + wn + nt * 16 + l15];
#pragma unroll
    for (int mt = 0; mt < 4; mt++)
#pragma unroll
        for (int r = 0; r < 4; r++) {
            const int m = bm + wm + mt * 16 + quad * 4 + r;
#pragma unroll
            for (int nt = 0; nt < 4; nt++) {
                const int n = bn + wn + nt * 16 + l15;
                out[(size_t)m * HID + n] = acc[mt][nt][r] + bv4[nt];
            }
        }
}

// ---------------------------------------------------------------------------
// MFMA flash attention v7: occupancy push.  v5 double-buffer structure (the
// proven 58.3us loop) with the 8 KB mask LDS evicted (mask2 read per-tile
// from global -- 256 B/wave-tile, L1/L2 resident) so LDS drops to 51200 B ->
// 3 blocks/CU = 24 waves/CU (was 2 blocks/16 waves).  VGPR=52 means waves
// were LDS-bound, so this is pure +50% TLP to fill the exp2/stall cycles.
// Triple-buffer/counted-vmcnt dropped: measured neutral (v6 vs v5).
// LDS: K bufs @0,8192 | V bufs @16384,24576 | P @32768 (8x2304) = 51200.
// Epilogue reuses [0,34816).
// ---------------------------------------------------------------------------
__global__ __launch_bounds__(512, 6) void attn_mfma(const u16* __restrict__ qb,
                                                    const u16* __restrict__ kb,
                                                    const u16* __restrict__ vtb,
                                                    const float* __restrict__ m2g,
                                                    u16* __restrict__ ctx)
{
    __shared__ __align__(16) char smem[51200];
    u16 (*Pw)[72] = (u16(*)[72])(smem + 32768 + (threadIdx.x >> 6) * 2304);

    const int t    = threadIdx.x;
    const int wave = t >> 6;
    const int lane = t & 63;
    const int l15  = lane & 15;
    const int quad = lane >> 4;

    const int bh = blockIdx.x & 31;       // XCD swizzle: bh fastest
    const int qt = blockIdx.x >> 5;       // 0..15
    const int b  = bh >> 4;
    const int hh = bh & 15;
    const int q0 = qt * 128;              // 128 q rows per block

    const size_t headoff = (size_t)(b * NH + hh) * SEQ * HD;
    const u16* kbase = kb + headoff;
    const u16* vbase = vtb + (size_t)(hh * HD) * VSTR + b * SEQ;
    const float* m2b = m2g + b * SEQ;

    bf16x8 Qf[2];
    {
        const int qrow = q0 + wave * 16 + l15;
#pragma unroll
        for (int ks = 0; ks < 2; ks++)
            Qf[ks] = *(const bf16x8*)(qb + headoff + (size_t)qrow * HD + ks * 32 + quad * 8);
    }

    f32x4 O[4];
#pragma unroll
    for (int mt = 0; mt < 4; mt++) O[mt] = (f32x4)0.0f;
    f32x4 Lacc = (f32x4)0.0f;             // lsum via MFMA (all-ones A fragment)
    bf16x8 ones;
#pragma unroll
    for (int j = 0; j < 8; j++) ones[j] = (short)0x3F80;   // bf16 1.0

    const int srow = lane >> 3;
    const int lcol = (lane & 7) ^ srow;       // XOR-swizzled staging chunk
    const int sw0 = ((quad)     ^ (l15 & 7)) * 8;
    const int sw1 = ((quad + 4) ^ (l15 & 7)) * 8;

    // wave w stages K rows [w*8,w*8+8) and V' d-rows [w*8,w*8+8) of each tile
    const u16* kp = kbase + (size_t)(wave * 8 + srow) * HD + lcol * 8;
    const u16* vp = vbase + (size_t)(wave * 8 + srow) * VSTR + lcol * 8;

    // stage tile 0 into buffer 0
    ldsload16(kp, smem + wave * 1024);
    ldsload16(vp, smem + 16384 + wave * 1024);

    for (int i = 0; i < 32; i++) {
        __syncthreads();   // drains tile-i loads; tile i-1 compute finished
        const int c0 = i * 64;
        const u16* Ks  = (const u16*)(smem + (i & 1) * 8192);
        const u16* Vts = (const u16*)(smem + 16384 + (i & 1) * 8192);
        if (i + 1 < 32) {
            const int cn = c0 + 64;
            char* nbK = smem + ((i + 1) & 1) * 8192;
            char* nbV = smem + 16384 + ((i + 1) & 1) * 8192;
            ldsload16(kp + (size_t)cn * HD, nbK + wave * 1024);
            ldsload16(vp + cn,              nbV + wave * 1024);
        }

        // S^T: D[m=kv][n=q] = sum_d K[kv][d] * Q[q][d]
        f32x4 St[4];
        __builtin_amdgcn_s_setprio(1);
#pragma unroll
        for (int mt = 0; mt < 4; mt++) {
            const int rb = (mt * 16 + l15) * 64;
            const bf16x8 ka0 = *(const bf16x8*)&Ks[rb + sw0];
            const bf16x8 ka1 = *(const bf16x8*)&Ks[rb + sw1];
            f32x4 a = (f32x4)0.0f;
            a = mfma16(ka0, Qf[0], a);
            a = mfma16(ka1, Qf[1], a);
            St[mt] = a;
        }
        __builtin_amdgcn_s_setprio(0);

        // p = exp2(score*C2 + mask2); packed bf16 P (mask2 from global, cached)
#pragma unroll
        for (int mt = 0; mt < 4; mt++) {
            const f32x4 mv = *(const f32x4*)(m2b + c0 + mt * 16 + quad * 4);
            float p0 = __builtin_amdgcn_exp2f(fmaf(St[mt][0], C2, mv[0]));
            float p1 = __builtin_amdgcn_exp2f(fmaf(St[mt][1], C2, mv[1]));
            float p2 = __builtin_amdgcn_exp2f(fmaf(St[mt][2], C2, mv[2]));
            float p3 = __builtin_amdgcn_exp2f(fmaf(St[mt][3], C2, mv[3]));
            uint2 w;
            w.x = pk_bf16(p0, p1);
            w.y = pk_bf16(p2, p3);
            *(uint2*)&Pw[l15][mt * 16 + quad * 4] = w;
        }

        const bf16x8 Pb0 = *(const bf16x8*)&Pw[l15][quad * 8];
        const bf16x8 Pb1 = *(const bf16x8*)&Pw[l15][32 + quad * 8];

        // O^T: D[m=d][n=q] += sum_kv V[kv][d] * P[q][kv]; Lacc += sum_kv P
        __builtin_amdgcn_s_setprio(1);
#pragma unroll
        for (int mt = 0; mt < 4; mt++) {
            const int rb = (mt * 16 + l15) * 64;
            const bf16x8 va0 = *(const bf16x8*)&Vts[rb + sw0];
            const bf16x8 va1 = *(const bf16x8*)&Vts[rb + sw1];
            O[mt] = mfma16(va0, Pb0, O[mt]);
            O[mt] = mfma16(va1, Pb1, O[mt]);
        }
        Lacc = mfma16(ones, Pb0, Lacc);
        Lacc = mfma16(ones, Pb1, Lacc);
        __builtin_amdgcn_s_setprio(0);
    }

    const float linv = 1.0f / Lacc[0];    // per-q (col=l15) denominator, all lanes

    __syncthreads();
    float* Ot = (float*)smem + wave * (16 * 68);
#pragma unroll
    for (int mt = 0; mt < 4; mt++) {
        f32x4 v = O[mt] * linv;
        *(f32x4*)(Ot + l15 * 68 + mt * 16 + quad * 4) = v;
    }
    __syncthreads();
    {
        const int ql  = lane >> 2;
        const int seg = lane & 3;
        const float* srcp = Ot + ql * 68 + seg * 16;
        u16* dstp = ctx + (size_t)(b * SEQ + q0 + wave * 16 + ql) * HID
                        + hh * 64 + seg * 16;
#pragma unroll
        for (int j = 0; j < 2; j++) {
            union { u16 s[8]; uint4 v; } p;
#pragma unroll
            for (int i = 0; i < 8; i++) p.s[i] = f2bf(srcp[j * 8 + i]);
            *(uint4*)(dstp + j * 8) = p.v;
        }
    }
}

// ---------------------------------------------------------------------------
extern "C" void kernel_launch(void* const* d_in, const int* in_sizes, int n_in,
                              void* d_out, int out_size, void* d_ws, size_t ws_size,
                              hipStream_t stream)
{
    const float* hs    = (const float*)d_in[0];
    const float* mask  = (const float*)d_in[1];
    const float* Wq    = (const float*)d_in[2];
    const float* bq    = (const float*)d_in[3];
    const float* Wk    = (const float*)d_in[4];
    const float* bk    = (const float*)d_in[5];
    const float* Wv    = (const float*)d_in[6];
    const float* bv    = (const float*)d_in[7];
    const float* Wd    = (const float*)d_in[8];
    const float* bd    = (const float*)d_in[9];
    const float* gamma = (const float*)d_in[10];
    const float* beta  = (const float*)d_in[11];
    float* out = (float*)d_out;

    const size_t NE = (size_t)MROWS * HID;
    u16* ws   = (u16*)d_ws;
    u16* h    = ws;                          // bf16 [MROWS][HID]
    u16* qbb  = ws + NE;                     // bf16 [B,NH,S,HD]
    u16* kbb  = qbb + NE;                    // bf16 [B,NH,S,HD]
    u16* vtb  = kbb + NE;                    // bf16 [HID][VSTR]
    u16* ctxb = vtb + (size_t)HID * VSTR;    // bf16 [MROWS][HID]
    u16* wqb  = ctxb + NE;
    u16* wkb  = wqb + HID * HID;
    u16* wvb  = wkb + HID * HID;
    u16* wdb  = wvb + HID * HID;
    float* m2 = (float*)(wdb + HID * HID);   // fp32 [MROWS] precomputed mask2

    prep_kernel<<<8196, 256, 0, stream>>>(hs, gamma, beta, h,
                                          Wq, Wk, Wv, Wd, wqb, wkb, wvb, wdb,
                                          mask, m2);

    qkv_gemm<<<768, 256, 0, stream>>>(h, wqb, wkb, wvb, bq, bk, bv, qbb, kbb, vtb);

    attn_mfma<<<512, 512, 0, stream>>>(qbb, kbb, vtb, m2, ctxb);

    out_gemm<<<256, 256, 0, stream>>>(ctxb, wdb, bd, out);
}

// Round 8
// 206.967 us; speedup vs baseline: 1.0155x; 1.0155x over previous
//
#include <hip/hip_runtime.h>
#include <hip/hip_bf16.h>
#include <math.h>

#define BATCH 2
#define SEQ   2048
#define HID   1024
#define NH    16
#define HD    64
#define MROWS (BATCH * SEQ)   // 4096
#define VSTR  4160            // padded row stride of V' (avoid 8192B channel camping)

typedef unsigned short u16;
typedef short bf16x8 __attribute__((ext_vector_type(8)));
typedef float f32x4  __attribute__((ext_vector_type(4)));

#define LOG2E 1.4426950408889634f
#define C2    (0.125f * LOG2E)      // score scale folded into log2 domain
#define M2F   23.083120f            // fixed softmax shift (shift-invariant)

static __device__ __forceinline__ u16 f2bf(float f) {
    union { float f; unsigned int u; } v; v.f = f;
    unsigned int r = (v.u + 0x7FFF + ((v.u >> 16) & 1)) >> 16;  // RNE
    return (u16)r;
}

static __device__ __forceinline__ unsigned int pk_bf16(float a, float b) {
    union { __hip_bfloat162 h; unsigned int u; } r;
    float2 f; f.x = a; f.y = b;
    r.h = __float22bfloat162_rn(f);   // packed cvt where HW supports it
    return r.u;
}

static __device__ __forceinline__ f32x4 mfma16(bf16x8 a, bf16x8 b, f32x4 c) {
    return __builtin_amdgcn_mfma_f32_16x16x32_bf16(a, b, c, 0, 0, 0);
}

// global -> LDS async copy, 16 B per lane; LDS dest = wave-uniform base + lane*16.
static __device__ __forceinline__ void ldsload16(const void* g, void* l) {
    __builtin_amdgcn_global_load_lds(
        (const __attribute__((address_space(1))) void*)(unsigned long long)(uintptr_t)g,
        (__attribute__((address_space(3))) void*)(unsigned int)(uintptr_t)l,
        16, 0, 0);
}

// ---------------------------------------------------------------------------
// Fused prep: [0,4096) weight cast; [4096,8192) LayerNorm; [8192,8196) mask2
// precompute: mask2[s] = -1000*(1-mask)*LOG2E - M2F.
// ---------------------------------------------------------------------------
__global__ __launch_bounds__(256) void prep_kernel(const float* __restrict__ x,
                                                   const float* __restrict__ gamma,
                                                   const float* __restrict__ beta,
                                                   u16* __restrict__ h,
                                                   const float* __restrict__ w0,
                                                   const float* __restrict__ w1,
                                                   const float* __restrict__ w2,
                                                   const float* __restrict__ w3,
                                                   u16* o0, u16* o1, u16* o2, u16* o3,
                                                   const float* __restrict__ maskg,
                                                   float* __restrict__ m2g)
{
    __shared__ float red[8];
    const int t = threadIdx.x;
    if (blockIdx.x >= 8192) {
        const int idx = ((blockIdx.x - 8192) * 256 + t) * 4;
        const float4 m = *(const float4*)(maskg + idx);
        float4 o;
        o.x = fmaf(-1000.0f * (1.0f - m.x), LOG2E, -M2F);
        o.y = fmaf(-1000.0f * (1.0f - m.y), LOG2E, -M2F);
        o.z = fmaf(-1000.0f * (1.0f - m.z), LOG2E, -M2F);
        o.w = fmaf(-1000.0f * (1.0f - m.w), LOG2E, -M2F);
        *(float4*)(m2g + idx) = o;
        return;
    }
    if (blockIdx.x < 4096) {
        const int blk = blockIdx.x;
        const int which = blk >> 10;
        const int lb = blk & 1023;
        const float* src = which == 0 ? w0 : which == 1 ? w1 : which == 2 ? w2 : w3;
        u16* dst = which == 0 ? o0 : which == 1 ? o1 : which == 2 ? o2 : o3;
        const int idx = (lb * 256 + t) * 4;
        const float4 f = *(const float4*)(src + idx);
        union { u16 s[4]; uint2 v; } p;
        p.s[0] = f2bf(f.x); p.s[1] = f2bf(f.y); p.s[2] = f2bf(f.z); p.s[3] = f2bf(f.w);
        *(uint2*)(dst + idx) = p.v;
        return;
    }
    const int row = blockIdx.x - 4096;
    const float4 xv = ((const float4*)(x + (size_t)row * HID))[t];
    float s  = xv.x + xv.y + xv.z + xv.w;
    float ss = xv.x * xv.x + xv.y * xv.y + xv.z * xv.z + xv.w * xv.w;
#pragma unroll
    for (int off = 32; off > 0; off >>= 1) {
        s  += __shfl_down(s, off);
        ss += __shfl_down(ss, off);
    }
    const int wid = t >> 6;
    if ((t & 63) == 0) { red[wid] = s; red[4 + wid] = ss; }
    __syncthreads();
    s  = red[0] + red[1] + red[2] + red[3];
    ss = red[4] + red[5] + red[6] + red[7];
    const float mu   = s * (1.0f / HID);
    const float var  = ss * (1.0f / HID) - mu * mu;
    const float rstd = rsqrtf(var + 1e-12f);
    const float4 g  = ((const float4*)gamma)[t];
    const float4 bb = ((const float4*)beta)[t];
    union { u16 s[4]; uint2 v; } p;
    p.s[0] = f2bf((xv.x - mu) * rstd * g.x + bb.x);
    p.s[1] = f2bf((xv.y - mu) * rstd * g.y + bb.y);
    p.s[2] = f2bf((xv.z - mu) * rstd * g.z + bb.z);
    p.s[3] = f2bf((xv.w - mu) * rstd * g.w + bb.w);
    ((uint2*)(h + (size_t)row * HID))[t] = p.v;
}

// ---------------------------------------------------------------------------
// MFMA GEMM core v2: 128x64 tile, BK=32, 4 waves 2x2 (wave = 64x32), dbuf.
// Smaller tile -> 2x the blocks of the old 128x128 -> 6 blocks/CU for qkv
// (24 waves/CU, 6/SIMD) and 2/CU for out_gemm.  These GEMMs are latency-
// bound (1-3 waves/SIMD before), so TLP is the binding resource.
// A[M,K], B[N,K] row-major bf16 (C = A * B^T).
// As = 8192 u16 (2 x 128x32), Bs = 4096 u16 (2 x 64x32).  LDS 24 KB.
// ---------------------------------------------------------------------------
static __device__ __forceinline__ void gemm_core64(const u16* __restrict__ A,
                                                   const u16* __restrict__ B,
                                                   int K, int bm, int bn,
                                                   u16* As, u16* Bs,
                                                   int wave, int lane,
                                                   f32x4 acc[4][2])
{
    const int l15  = lane & 15;
    const int quad = lane >> 4;
    const int wm = (wave >> 1) * 64;
    const int wn = (wave & 1) * 32;

    const int c1 = wave * 64 + lane;      // 0..255
    const int c2 = c1 + 256;
    const u16* A1 = A + (size_t)(bm + (c1 >> 2)) * K + (c1 & 3) * 8;
    const u16* A2 = A + (size_t)(bm + (c2 >> 2)) * K + (c2 & 3) * 8;
    const u16* B1 = B + (size_t)(bn + (c1 >> 2)) * K + (c1 & 3) * 8;
    const int o1 = wave * 512;            // A rows wave*16..+16
    const int o2 = 2048 + wave * 512;     // A rows 64+wave*16..+16
    const int ob = wave * 512;            // B rows wave*16..+16

    // stage K-step 0 into buffer 0
    ldsload16(A1, As + o1);
    ldsload16(A2, As + o2);
    ldsload16(B1, Bs + ob);

    const int nstep = K >> 5;
    for (int i = 0; i < nstep; i++) {
        __syncthreads();                  // drains step-i loads (vmcnt 0)
        const int ca = (i & 1) * 4096;
        const int cbb = (i & 1) * 2048;
        if (i + 1 < nstep) {
            const int na = ((i + 1) & 1) * 4096;
            const int nb = ((i + 1) & 1) * 2048;
            const int k0 = (i + 1) * 32;
            ldsload16(A1 + k0, As + na + o1);
            ldsload16(A2 + k0, As + na + o2);
            ldsload16(B1 + k0, Bs + nb + ob);
        }
        bf16x8 af[4], bfr[2];
#pragma unroll
        for (int mt = 0; mt < 4; mt++)
            af[mt] = *(const bf16x8*)&As[ca + (wm + mt * 16 + l15) * 32 + quad * 8];
#pragma unroll
        for (int nt = 0; nt < 2; nt++)
            bfr[nt] = *(const bf16x8*)&Bs[cbb + (wn + nt * 16 + l15) * 32 + quad * 8];
#pragma unroll
        for (int mt = 0; mt < 4; mt++)
#pragma unroll
            for (int nt = 0; nt < 2; nt++)
                acc[mt][nt] = mfma16(af[mt], bfr[nt], acc[mt][nt]);
    }
}

// ---------------------------------------------------------------------------
// Fused QKV, 128x64 tiles.  Blocks 0..511: q.  512..1023: k.
// 1024..1535: V' = Wv*h^T (bm over Wv rows, bn over h rows).
// ---------------------------------------------------------------------------
__global__ __launch_bounds__(256, 6) void qkv_gemm(const u16* __restrict__ h,
                                                   const u16* __restrict__ wq,
                                                   const u16* __restrict__ wk,
                                                   const u16* __restrict__ wv,
                                                   const float* __restrict__ bq,
                                                   const float* __restrict__ bk,
                                                   const float* __restrict__ bv,
                                                   u16* __restrict__ qo,
                                                   u16* __restrict__ ko,
                                                   u16* __restrict__ vo)
{
    __shared__ u16 As[8192];
    __shared__ u16 Bs[4096];
    const int blk  = blockIdx.x;
    const int wave = threadIdx.x >> 6;
    const int lane = threadIdx.x & 63;
    const int l15  = lane & 15;
    const int quad = lane >> 4;
    const int wm = (wave >> 1) * 64;
    const int wn = (wave & 1) * 32;

    f32x4 acc[4][2];
#pragma unroll
    for (int mt = 0; mt < 4; mt++)
#pragma unroll
        for (int nt = 0; nt < 2; nt++) acc[mt][nt] = (f32x4)0.0f;

    if (blk < 1024) {
        const u16* W     = (blk < 512) ? wq : wk;
        const float* bia = (blk < 512) ? bq : bk;
        u16* out         = (blk < 512) ? qo : ko;
        const int local = blk & 511;
        const int bm = (local >> 4) * 128;    // 32 M-tiles
        const int bn = (local & 15) * 64;     // 16 N-tiles
        gemm_core64(h, W, HID, bm, bn, As, Bs, wave, lane, acc);

        float bv2[2];
#pragma unroll
        for (int nt = 0; nt < 2; nt++) bv2[nt] = bia[bn + wn + nt * 16 + l15];
#pragma unroll
        for (int mt = 0; mt < 4; mt++)
#pragma unroll
            for (int r = 0; r < 4; r++) {
                const int m  = bm + wm + mt * 16 + quad * 4 + r;
                const int bI = m >> 11;
                const int sI = m & (SEQ - 1);
#pragma unroll
                for (int nt = 0; nt < 2; nt++) {
                    const int n  = bn + wn + nt * 16 + l15;
                    const int hh = n >> 6;
                    const int d  = n & 63;
                    out[(((size_t)(bI * NH + hh) * SEQ + sI) << 6) + d] =
                        f2bf(acc[mt][nt][r] + bv2[nt]);
                }
            }
    } else {
        const int local = blk - 1024;
        const int bm = (local & 7) * 128;     // 8 tiles over Wv rows (1024)
        const int bn = (local >> 3) * 64;     // 64 tiles over h rows (4096)
        gemm_core64(wv, h, HID, bm, bn, As, Bs, wave, lane, acc);

#pragma unroll
        for (int mt = 0; mt < 4; mt++) {
            const f32x4 bm4 = *(const f32x4*)&bv[bm + wm + mt * 16 + quad * 4];
#pragma unroll
            for (int r = 0; r < 4; r++) {
                const int row = bm + wm + mt * 16 + quad * 4 + r;
#pragma unroll
                for (int nt = 0; nt < 2; nt++) {
                    const int col = bn + wn + nt * 16 + l15;
                    vo[(size_t)row * VSTR + col] = f2bf(acc[mt][nt][r] + bm4[r]);
                }
            }
        }
    }
}

// ---------------------------------------------------------------------------
// Output projection, 128x64 tiles: out = ctx * Wd^T + bd, fp32 out.  512 blks.
// ---------------------------------------------------------------------------
__global__ __launch_bounds__(256, 6) void out_gemm(const u16* __restrict__ ctx,
                                                   const u16* __restrict__ wd,
                                                   const float* __restrict__ bd,
                                                   float* __restrict__ out)
{
    __shared__ u16 As[8192];
    __shared__ u16 Bs[4096];
    const int blk  = blockIdx.x;
    const int wave = threadIdx.x >> 6;
    const int lane = threadIdx.x & 63;
    const int l15  = lane & 15;
    const int quad = lane >> 4;
    const int wm = (wave >> 1) * 64;
    const int wn = (wave & 1) * 32;
    const int bm = (blk >> 4) * 128;
    const int bn = (blk & 15) * 64;

    f32x4 acc[4][2];
#pragma unroll
    for (int mt = 0; mt < 4; mt++)
#pragma unroll
        for (int nt = 0; nt < 2; nt++) acc[mt][nt] = (f32x4)0.0f;

    gemm_core64(ctx, wd, HID, bm, bn, As, Bs, wave, lane, acc);

    float bv2[2];
#pragma unroll
    for (int nt = 0; nt < 2; nt++) bv2[nt] = bd[bn + wn + nt * 16 + l15];
#pragma unroll
    for (int mt = 0; mt < 4; mt++)
#pragma unroll
        for (int r = 0; r < 4; r++) {
            const int m = bm + wm + mt * 16 + quad * 4 + r;
#pragma unroll
            for (int nt = 0; nt < 2; nt++) {
                const int n = bn + wn + nt * 16 + l15;
                out[(size_t)m * HID + n] = acc[mt][nt][r] + bv2[nt];
            }
        }
}

// ---------------------------------------------------------------------------
// MFMA flash attention (v5, proven 58.3us): 8-wave blocks (128 q rows), K/V
// double buffer shared by all waves, mask2 staged in LDS once, lsum via MFMA
// with all-ones A fragment.  LDS: K @0,8192 | V @16384,24576 | P @32768
// (8x2304) | mask @51200 (8 KB) = 59392.  Grid 512 = 2 blocks/CU.
// ---------------------------------------------------------------------------
__global__ __launch_bounds__(512, 4) void attn_mfma(const u16* __restrict__ qb,
                                                    const u16* __restrict__ kb,
                                                    const u16* __restrict__ vtb,
                                                    const float* __restrict__ m2g,
                                                    u16* __restrict__ ctx)
{
    __shared__ __align__(16) char smem[59392];
    u16 (*Pw)[72] = (u16(*)[72])(smem + 32768 + (threadIdx.x >> 6) * 2304);
    float* mlds = (float*)(smem + 51200);

    const int t    = threadIdx.x;
    const int wave = t >> 6;
    const int lane = t & 63;
    const int l15  = lane & 15;
    const int quad = lane >> 4;

    const int bh = blockIdx.x & 31;       // XCD swizzle: bh fastest
    const int qt = blockIdx.x >> 5;       // 0..15
    const int b  = bh >> 4;
    const int hh = bh & 15;
    const int q0 = qt * 128;              // 128 q rows per block

    const size_t headoff = (size_t)(b * NH + hh) * SEQ * HD;
    const u16* kbase = kb + headoff;
    const u16* vbase = vtb + (size_t)(hh * HD) * VSTR + b * SEQ;
    const float* m2b = m2g + b * SEQ;

    // stage mask2 row (2048 f32 = 8 KB) into LDS once; 512 threads x 1 float4
    ((float4*)mlds)[t] = ((const float4*)m2b)[t];

    bf16x8 Qf[2];
    {
        const int qrow = q0 + wave * 16 + l15;
#pragma unroll
        for (int ks = 0; ks < 2; ks++)
            Qf[ks] = *(const bf16x8*)(qb + headoff + (size_t)qrow * HD + ks * 32 + quad * 8);
    }

    f32x4 O[4];
#pragma unroll
    for (int mt = 0; mt < 4; mt++) O[mt] = (f32x4)0.0f;
    f32x4 Lacc = (f32x4)0.0f;             // lsum via MFMA (all rows identical)
    bf16x8 ones;
#pragma unroll
    for (int j = 0; j < 8; j++) ones[j] = (short)0x3F80;   // bf16 1.0

    const int srow = lane >> 3;
    const int lcol = (lane & 7) ^ srow;       // XOR-swizzled staging chunk
    const int sw0 = ((quad)     ^ (l15 & 7)) * 8;
    const int sw1 = ((quad + 4) ^ (l15 & 7)) * 8;

    // wave w stages K rows [w*8,w*8+8) and V' d-rows [w*8,w*8+8) of each tile
    const u16* kp = kbase + (size_t)(wave * 8 + srow) * HD + lcol * 8;
    const u16* vp = vbase + (size_t)(wave * 8 + srow) * VSTR + lcol * 8;

    // stage tile 0 into buffer 0
    ldsload16(kp, smem + wave * 1024);
    ldsload16(vp, smem + 16384 + wave * 1024);

    for (int i = 0; i < 32; i++) {
        __syncthreads();   // drains tile-i loads; tile i-1 compute finished
        const int c0 = i * 64;
        const u16* Ks  = (const u16*)(smem + (i & 1) * 8192);
        const u16* Vts = (const u16*)(smem + 16384 + (i & 1) * 8192);
        if (i + 1 < 32) {
            const int cn = c0 + 64;
            char* nbK = smem + ((i + 1) & 1) * 8192;
            char* nbV = smem + 16384 + ((i + 1) & 1) * 8192;
            ldsload16(kp + (size_t)cn * HD, nbK + wave * 1024);
            ldsload16(vp + cn,              nbV + wave * 1024);
        }

        // S^T: D[m=kv][n=q] = sum_d K[kv][d] * Q[q][d]
        f32x4 St[4];
        __builtin_amdgcn_s_setprio(1);
#pragma unroll
        for (int mt = 0; mt < 4; mt++) {
            const int rb = (mt * 16 + l15) * 64;
            const bf16x8 ka0 = *(const bf16x8*)&Ks[rb + sw0];
            const bf16x8 ka1 = *(const bf16x8*)&Ks[rb + sw1];
            f32x4 a = (f32x4)0.0f;
            a = mfma16(ka0, Qf[0], a);
            a = mfma16(ka1, Qf[1], a);
            St[mt] = a;
        }
        __builtin_amdgcn_s_setprio(0);

        // p = exp2(score*C2 + mask2); packed bf16 P (lsum via MFMA below)
#pragma unroll
        for (int mt = 0; mt < 4; mt++) {
            const f32x4 mv = *(const f32x4*)(mlds + c0 + mt * 16 + quad * 4);
            float p0 = __builtin_amdgcn_exp2f(fmaf(St[mt][0], C2, mv[0]));
            float p1 = __builtin_amdgcn_exp2f(fmaf(St[mt][1], C2, mv[1]));
            float p2 = __builtin_amdgcn_exp2f(fmaf(St[mt][2], C2, mv[2]));
            float p3 = __builtin_amdgcn_exp2f(fmaf(St[mt][3], C2, mv[3]));
            uint2 w;
            w.x = pk_bf16(p0, p1);
            w.y = pk_bf16(p2, p3);
            *(uint2*)&Pw[l15][mt * 16 + quad * 4] = w;
        }

        const bf16x8 Pb0 = *(const bf16x8*)&Pw[l15][quad * 8];
        const bf16x8 Pb1 = *(const bf16x8*)&Pw[l15][32 + quad * 8];

        // O^T: D[m=d][n=q] += sum_kv V[kv][d] * P[q][kv]; Lacc += sum_kv P
        __builtin_amdgcn_s_setprio(1);
#pragma unroll
        for (int mt = 0; mt < 4; mt++) {
            const int rb = (mt * 16 + l15) * 64;
            const bf16x8 va0 = *(const bf16x8*)&Vts[rb + sw0];
            const bf16x8 va1 = *(const bf16x8*)&Vts[rb + sw1];
            O[mt] = mfma16(va0, Pb0, O[mt]);
            O[mt] = mfma16(va1, Pb1, O[mt]);
        }
        Lacc = mfma16(ones, Pb0, Lacc);
        Lacc = mfma16(ones, Pb1, Lacc);
        __builtin_amdgcn_s_setprio(0);
    }

    const float linv = 1.0f / Lacc[0];    // per-q (col=l15) denominator, all lanes

    __syncthreads();
    float* Ot = (float*)smem + wave * (16 * 68);
#pragma unroll
    for (int mt = 0; mt < 4; mt++) {
        f32x4 v = O[mt] * linv;
        *(f32x4*)(Ot + l15 * 68 + mt * 16 + quad * 4) = v;
    }
    __syncthreads();
    {
        const int ql  = lane >> 2;
        const int seg = lane & 3;
        const float* srcp = Ot + ql * 68 + seg * 16;
        u16* dstp = ctx + (size_t)(b * SEQ + q0 + wave * 16 + ql) * HID
                        + hh * 64 + seg * 16;
#pragma unroll
        for (int j = 0; j < 2; j++) {
            union { u16 s[8]; uint4 v; } p;
#pragma unroll
            for (int i = 0; i < 8; i++) p.s[i] = f2bf(srcp[j * 8 + i]);
            *(uint4*)(dstp + j * 8) = p.v;
        }
    }
}

// ---------------------------------------------------------------------------
extern "C" void kernel_launch(void* const* d_in, const int* in_sizes, int n_in,
                              void* d_out, int out_size, void* d_ws, size_t ws_size,
                              hipStream_t stream)
{
    const float* hs    = (const float*)d_in[0];
    const float* mask  = (const float*)d_in[1];
    const float* Wq    = (const float*)d_in[2];
    const float* bq    = (const float*)d_in[3];
    const float* Wk    = (const float*)d_in[4];
    const float* bk    = (const float*)d_in[5];
    const float* Wv    = (const float*)d_in[6];
    const float* bv    = (const float*)d_in[7];
    const float* Wd    = (const float*)d_in[8];
    const float* bd    = (const float*)d_in[9];
    const float* gamma = (const float*)d_in[10];
    const float* beta  = (const float*)d_in[11];
    float* out = (float*)d_out;

    const size_t NE = (size_t)MROWS * HID;
    u16* ws   = (u16*)d_ws;
    u16* h    = ws;                          // bf16 [MROWS][HID]
    u16* qbb  = ws + NE;                     // bf16 [B,NH,S,HD]
    u16* kbb  = qbb + NE;                    // bf16 [B,NH,S,HD]
    u16* vtb  = kbb + NE;                    // bf16 [HID][VSTR]
    u16* ctxb = vtb + (size_t)HID * VSTR;    // bf16 [MROWS][HID]
    u16* wqb  = ctxb + NE;
    u16* wkb  = wqb + HID * HID;
    u16* wvb  = wkb + HID * HID;
    u16* wdb  = wvb + HID * HID;
    float* m2 = (float*)(wdb + HID * HID);   // fp32 [MROWS] precomputed mask2

    prep_kernel<<<8196, 256, 0, stream>>>(hs, gamma, beta, h,
                                          Wq, Wk, Wv, Wd, wqb, wkb, wvb, wdb,
                                          mask, m2);

    qkv_gemm<<<1536, 256, 0, stream>>>(h, wqb, wkb, wvb, bq, bk, bv, qbb, kbb, vtb);

    attn_mfma<<<512, 512, 0, stream>>>(qbb, kbb, vtb, m2, ctxb);

    out_gemm<<<512, 256, 0, stream>>>(ctxb, wdb, bd, out);
}

// Round 9
// 199.010 us; speedup vs baseline: 1.0562x; 1.0400x over previous
//
#include <hip/hip_runtime.h>
#include <hip/hip_bf16.h>
#include <math.h>

#define BATCH 2
#define SEQ   2048
#define HID   1024
#define NH    16
#define HD    64
#define MROWS (BATCH * SEQ)   // 4096
#define VSTR  4160            // padded row stride of V' (avoid 8192B channel camping)

typedef unsigned short u16;
typedef short bf16x8 __attribute__((ext_vector_type(8)));
typedef float f32x4  __attribute__((ext_vector_type(4)));

#define LOG2E 1.4426950408889634f
#define C2    (0.125f * LOG2E)      // score scale folded into log2 domain
#define M2F   23.083120f            // fixed softmax shift (shift-invariant)

static __device__ __forceinline__ u16 f2bf(float f) {
    union { float f; unsigned int u; } v; v.f = f;
    unsigned int r = (v.u + 0x7FFF + ((v.u >> 16) & 1)) >> 16;  // RNE
    return (u16)r;
}

static __device__ __forceinline__ unsigned int pk_bf16(float a, float b) {
    union { __hip_bfloat162 h; unsigned int u; } r;
    float2 f; f.x = a; f.y = b;
    r.h = __float22bfloat162_rn(f);   // packed cvt where HW supports it
    return r.u;
}

static __device__ __forceinline__ f32x4 mfma16(bf16x8 a, bf16x8 b, f32x4 c) {
    return __builtin_amdgcn_mfma_f32_16x16x32_bf16(a, b, c, 0, 0, 0);
}

// global -> LDS async copy, 16 B per lane; LDS dest = wave-uniform base + lane*16.
static __device__ __forceinline__ void ldsload16(const void* g, void* l) {
    __builtin_amdgcn_global_load_lds(
        (const __attribute__((address_space(1))) void*)(unsigned long long)(uintptr_t)g,
        (__attribute__((address_space(3))) void*)(unsigned int)(uintptr_t)l,
        16, 0, 0);
}

// ---------------------------------------------------------------------------
// Fused prep: [0,4096) weight cast; [4096,8192) LayerNorm; [8192,8196) mask2
// precompute: mask2[s] = -1000*(1-mask)*LOG2E - M2F.
// ---------------------------------------------------------------------------
__global__ __launch_bounds__(256) void prep_kernel(const float* __restrict__ x,
                                                   const float* __restrict__ gamma,
                                                   const float* __restrict__ beta,
                                                   u16* __restrict__ h,
                                                   const float* __restrict__ w0,
                                                   const float* __restrict__ w1,
                                                   const float* __restrict__ w2,
                                                   const float* __restrict__ w3,
                                                   u16* o0, u16* o1, u16* o2, u16* o3,
                                                   const float* __restrict__ maskg,
                                                   float* __restrict__ m2g)
{
    __shared__ float red[8];
    const int t = threadIdx.x;
    if (blockIdx.x >= 8192) {
        const int idx = ((blockIdx.x - 8192) * 256 + t) * 4;
        const float4 m = *(const float4*)(maskg + idx);
        float4 o;
        o.x = fmaf(-1000.0f * (1.0f - m.x), LOG2E, -M2F);
        o.y = fmaf(-1000.0f * (1.0f - m.y), LOG2E, -M2F);
        o.z = fmaf(-1000.0f * (1.0f - m.z), LOG2E, -M2F);
        o.w = fmaf(-1000.0f * (1.0f - m.w), LOG2E, -M2F);
        *(float4*)(m2g + idx) = o;
        return;
    }
    if (blockIdx.x < 4096) {
        const int blk = blockIdx.x;
        const int which = blk >> 10;
        const int lb = blk & 1023;
        const float* src = which == 0 ? w0 : which == 1 ? w1 : which == 2 ? w2 : w3;
        u16* dst = which == 0 ? o0 : which == 1 ? o1 : which == 2 ? o2 : o3;
        const int idx = (lb * 256 + t) * 4;
        const float4 f = *(const float4*)(src + idx);
        union { u16 s[4]; uint2 v; } p;
        p.s[0] = f2bf(f.x); p.s[1] = f2bf(f.y); p.s[2] = f2bf(f.z); p.s[3] = f2bf(f.w);
        *(uint2*)(dst + idx) = p.v;
        return;
    }
    const int row = blockIdx.x - 4096;
    const float4 xv = ((const float4*)(x + (size_t)row * HID))[t];
    float s  = xv.x + xv.y + xv.z + xv.w;
    float ss = xv.x * xv.x + xv.y * xv.y + xv.z * xv.z + xv.w * xv.w;
#pragma unroll
    for (int off = 32; off > 0; off >>= 1) {
        s  += __shfl_down(s, off);
        ss += __shfl_down(ss, off);
    }
    const int wid = t >> 6;
    if ((t & 63) == 0) { red[wid] = s; red[4 + wid] = ss; }
    __syncthreads();
    s  = red[0] + red[1] + red[2] + red[3];
    ss = red[4] + red[5] + red[6] + red[7];
    const float mu   = s * (1.0f / HID);
    const float var  = ss * (1.0f / HID) - mu * mu;
    const float rstd = rsqrtf(var + 1e-12f);
    const float4 g  = ((const float4*)gamma)[t];
    const float4 bb = ((const float4*)beta)[t];
    union { u16 s[4]; uint2 v; } p;
    p.s[0] = f2bf((xv.x - mu) * rstd * g.x + bb.x);
    p.s[1] = f2bf((xv.y - mu) * rstd * g.y + bb.y);
    p.s[2] = f2bf((xv.z - mu) * rstd * g.z + bb.z);
    p.s[3] = f2bf((xv.w - mu) * rstd * g.w + bb.w);
    ((uint2*)(h + (size_t)row * HID))[t] = p.v;
}

// ---------------------------------------------------------------------------
// MFMA GEMM core, double-buffered: 128x128 tile, BK=32, 4 waves 2x2, wave=64x64.
// A[M,K], B[N,K] row-major bf16 (C = A * B^T).  As/Bs are 8192-u16 (2 buffers).
// ---------------------------------------------------------------------------
static __device__ __forceinline__ void gemm_core(const u16* __restrict__ A,
                                                 const u16* __restrict__ B,
                                                 int K, int bm, int bn,
                                                 u16* As, u16* Bs,
                                                 int wave, int lane,
                                                 f32x4 acc[4][4])
{
    const int l15  = lane & 15;
    const int quad = lane >> 4;
    const int wm = (wave >> 1) * 64;
    const int wn = (wave & 1) * 64;

    const int c1 = wave * 64 + lane;
    const int c2 = c1 + 256;
    const u16* A1 = A + (size_t)(bm + (c1 >> 2)) * K + (c1 & 3) * 8;
    const u16* A2 = A + (size_t)(bm + (c2 >> 2)) * K + (c2 & 3) * 8;
    const u16* B1 = B + (size_t)(bn + (c1 >> 2)) * K + (c1 & 3) * 8;
    const u16* B2 = B + (size_t)(bn + (c2 >> 2)) * K + (c2 & 3) * 8;
    const int o1 = wave * 512;
    const int o2 = 2048 + wave * 512;

    // stage K-step 0 into buffer 0
    ldsload16(A1, As + o1);
    ldsload16(A2, As + o2);
    ldsload16(B1, Bs + o1);
    ldsload16(B2, Bs + o2);

    const int nstep = K >> 5;
    for (int i = 0; i < nstep; i++) {
        __syncthreads();                      // drains step-i loads (vmcnt 0)
        const int cb = (i & 1) * 4096;
        if (i + 1 < nstep) {
            const int nb = ((i + 1) & 1) * 4096;
            const int k0 = (i + 1) * 32;
            ldsload16(A1 + k0, As + nb + o1);
            ldsload16(A2 + k0, As + nb + o2);
            ldsload16(B1 + k0, Bs + nb + o1);
            ldsload16(B2 + k0, Bs + nb + o2);
        }
        bf16x8 af[4], bfr[4];
#pragma unroll
        for (int mt = 0; mt < 4; mt++)
            af[mt] = *(const bf16x8*)&As[cb + (wm + mt * 16 + l15) * 32 + quad * 8];
#pragma unroll
        for (int nt = 0; nt < 4; nt++)
            bfr[nt] = *(const bf16x8*)&Bs[cb + (wn + nt * 16 + l15) * 32 + quad * 8];
#pragma unroll
        for (int mt = 0; mt < 4; mt++)
#pragma unroll
            for (int nt = 0; nt < 4; nt++)
                acc[mt][nt] = mfma16(af[mt], bfr[nt], acc[mt][nt]);
    }
}

// ---------------------------------------------------------------------------
// Fused QKV, 128x128 tiles, XCD-chunked swizzle for L2 locality.
// Logical blocks 0..511: q/k interleaved pairs (blk&1 = proj) sharing (bm,bn)
//   -> adjacent blocks in a chunk reuse the same A(h) panel in that XCD's L2.
// Logical 512..767: V' = Wv*h^T, bm-fastest so the h-panel (B) is reused 8x
//   within a chunk and wv (2 MB) stays L2-resident.
// ---------------------------------------------------------------------------
__global__ __launch_bounds__(256) void qkv_gemm(const u16* __restrict__ h,
                                                const u16* __restrict__ wq,
                                                const u16* __restrict__ wk,
                                                const u16* __restrict__ wv,
                                                const float* __restrict__ bq,
                                                const float* __restrict__ bk,
                                                const float* __restrict__ bv,
                                                u16* __restrict__ qo,
                                                u16* __restrict__ ko,
                                                u16* __restrict__ vo)
{
    __shared__ u16 As[8192];
    __shared__ u16 Bs[8192];
    // bijective chunked XCD swizzle (768 % 8 == 0): XCD x gets logical
    // [x*96, (x+1)*96) -> consecutive logical blocks share an L2.
    const int blk  = (blockIdx.x & 7) * 96 + (blockIdx.x >> 3);
    const int wave = threadIdx.x >> 6;
    const int lane = threadIdx.x & 63;
    const int l15  = lane & 15;
    const int quad = lane >> 4;
    const int wm = (wave >> 1) * 64;
    const int wn = (wave & 1) * 64;

    f32x4 acc[4][4];
#pragma unroll
    for (int mt = 0; mt < 4; mt++)
#pragma unroll
        for (int nt = 0; nt < 4; nt++) acc[mt][nt] = (f32x4)0.0f;

    if (blk < 512) {
        const int proj  = blk & 1;            // 0=q, 1=k (pairs share A panel)
        const int pair  = blk >> 1;           // 0..255
        const u16* W     = proj ? wk : wq;
        const float* bia = proj ? bk : bq;
        u16* out         = proj ? ko : qo;
        const int bm = (pair >> 3) * 128;     // 32 M-tiles
        const int bn = (pair & 7) * 128;      // 8 N-tiles (fast within pair idx)
        gemm_core(h, W, HID, bm, bn, As, Bs, wave, lane, acc);

        float bv4[4];
#pragma unroll
        for (int nt = 0; nt < 4; nt++) bv4[nt] = bia[bn + wn + nt * 16 + l15];
#pragma unroll
        for (int mt = 0; mt < 4; mt++)
#pragma unroll
            for (int r = 0; r < 4; r++) {
                const int m  = bm + wm + mt * 16 + quad * 4 + r;
                const int bI = m >> 11;
                const int sI = m & (SEQ - 1);
#pragma unroll
                for (int nt = 0; nt < 4; nt++) {
                    const int n  = bn + wn + nt * 16 + l15;
                    const int hh = n >> 6;
                    const int d  = n & 63;
                    out[(((size_t)(bI * NH + hh) * SEQ + sI) << 6) + d] =
                        f2bf(acc[mt][nt][r] + bv4[nt]);
                }
            }
    } else {
        const int local = blk - 512;          // 0..255
        const int bm = (local & 7) * 128;     // bm-fastest: 8 tiles over Wv rows
        const int bn = (local >> 3) * 128;    // 32 tiles over h rows
        gemm_core(wv, h, HID, bm, bn, As, Bs, wave, lane, acc);

#pragma unroll
        for (int mt = 0; mt < 4; mt++) {
            const f32x4 bm4 = *(const f32x4*)&bv[bm + wm + mt * 16 + quad * 4];
#pragma unroll
            for (int r = 0; r < 4; r++) {
                const int row = bm + wm + mt * 16 + quad * 4 + r;
#pragma unroll
                for (int nt = 0; nt < 4; nt++) {
                    const int col = bn + wn + nt * 16 + l15;
                    vo[(size_t)row * VSTR + col] = f2bf(acc[mt][nt][r] + bm4[r]);
                }
            }
        }
    }
}

// ---------------------------------------------------------------------------
// MFMA GEMM core v2: 128x64 tile, BK=32, 4 waves 2x2 (wave = 64x32), dbuf.
// As = 8192 u16 (2 x 128x32), Bs = 4096 u16 (2 x 64x32).  LDS 24 KB.
// ---------------------------------------------------------------------------
static __device__ __forceinline__ void gemm_core64(const u16* __restrict__ A,
                                                   const u16* __restrict__ B,
                                                   int K, int bm, int bn,
                                                   u16* As, u16* Bs,
                                                   int wave, int lane,
                                                   f32x4 acc[4][2])
{
    const int l15  = lane & 15;
    const int quad = lane >> 4;
    const int wm = (wave >> 1) * 64;
    const int wn = (wave & 1) * 32;

    const int c1 = wave * 64 + lane;      // 0..255
    const int c2 = c1 + 256;
    const u16* A1 = A + (size_t)(bm + (c1 >> 2)) * K + (c1 & 3) * 8;
    const u16* A2 = A + (size_t)(bm + (c2 >> 2)) * K + (c2 & 3) * 8;
    const u16* B1 = B + (size_t)(bn + (c1 >> 2)) * K + (c1 & 3) * 8;
    const int o1 = wave * 512;            // A rows wave*16..+16
    const int o2 = 2048 + wave * 512;     // A rows 64+wave*16..+16
    const int ob = wave * 512;            // B rows wave*16..+16

    // stage K-step 0 into buffer 0
    ldsload16(A1, As + o1);
    ldsload16(A2, As + o2);
    ldsload16(B1, Bs + ob);

    const int nstep = K >> 5;
    for (int i = 0; i < nstep; i++) {
        __syncthreads();                  // drains step-i loads (vmcnt 0)
        const int ca = (i & 1) * 4096;
        const int cbb = (i & 1) * 2048;
        if (i + 1 < nstep) {
            const int na = ((i + 1) & 1) * 4096;
            const int nb = ((i + 1) & 1) * 2048;
            const int k0 = (i + 1) * 32;
            ldsload16(A1 + k0, As + na + o1);
            ldsload16(A2 + k0, As + na + o2);
            ldsload16(B1 + k0, Bs + nb + ob);
        }
        bf16x8 af[4], bfr[2];
#pragma unroll
        for (int mt = 0; mt < 4; mt++)
            af[mt] = *(const bf16x8*)&As[ca + (wm + mt * 16 + l15) * 32 + quad * 8];
#pragma unroll
        for (int nt = 0; nt < 2; nt++)
            bfr[nt] = *(const bf16x8*)&Bs[cbb + (wn + nt * 16 + l15) * 32 + quad * 8];
#pragma unroll
        for (int mt = 0; mt < 4; mt++)
#pragma unroll
            for (int nt = 0; nt < 2; nt++)
                acc[mt][nt] = mfma16(af[mt], bfr[nt], acc[mt][nt]);
    }
}

// ---------------------------------------------------------------------------
// Output projection, 128x64 tiles + XCD-chunked swizzle, bn-fastest:
// chunk of 64 = 4 A(ctx) panels (1 MB) + full wd (2 MB) -> L2-resident.
// ---------------------------------------------------------------------------
__global__ __launch_bounds__(256, 6) void out_gemm(const u16* __restrict__ ctx,
                                                   const u16* __restrict__ wd,
                                                   const float* __restrict__ bd,
                                                   float* __restrict__ out)
{
    __shared__ u16 As[8192];
    __shared__ u16 Bs[4096];
    const int blk  = (blockIdx.x & 7) * 64 + (blockIdx.x >> 3);  // 512 % 8 == 0
    const int wave = threadIdx.x >> 6;
    const int lane = threadIdx.x & 63;
    const int l15  = lane & 15;
    const int quad = lane >> 4;
    const int wm = (wave >> 1) * 64;
    const int wn = (wave & 1) * 32;
    const int bm = (blk >> 4) * 128;      // 32 M-tiles
    const int bn = (blk & 15) * 64;       // 16 N-tiles, fastest

    f32x4 acc[4][2];
#pragma unroll
    for (int mt = 0; mt < 4; mt++)
#pragma unroll
        for (int nt = 0; nt < 2; nt++) acc[mt][nt] = (f32x4)0.0f;

    gemm_core64(ctx, wd, HID, bm, bn, As, Bs, wave, lane, acc);

    float bv2[2];
#pragma unroll
    for (int nt = 0; nt < 2; nt++) bv2[nt] = bd[bn + wn + nt * 16 + l15];
#pragma unroll
    for (int mt = 0; mt < 4; mt++)
#pragma unroll
        for (int r = 0; r < 4; r++) {
            const int m = bm + wm + mt * 16 + quad * 4 + r;
#pragma unroll
            for (int nt = 0; nt < 2; nt++) {
                const int n = bn + wn + nt * 16 + l15;
                out[(size_t)m * HID + n] = acc[mt][nt][r] + bv2[nt];
            }
        }
}

// ---------------------------------------------------------------------------
// MFMA flash attention (v5, measured 56.5us): 8-wave blocks (128 q rows), K/V
// double buffer shared by all waves, mask2 staged in LDS once, lsum via MFMA
// with all-ones A fragment.  LDS: K @0,8192 | V @16384,24576 | P @32768
// (8x2304) | mask @51200 (8 KB) = 59392.  Grid 512 = 2 blocks/CU.
// ---------------------------------------------------------------------------
__global__ __launch_bounds__(512, 4) void attn_mfma(const u16* __restrict__ qb,
                                                    const u16* __restrict__ kb,
                                                    const u16* __restrict__ vtb,
                                                    const float* __restrict__ m2g,
                                                    u16* __restrict__ ctx)
{
    __shared__ __align__(16) char smem[59392];
    u16 (*Pw)[72] = (u16(*)[72])(smem + 32768 + (threadIdx.x >> 6) * 2304);
    float* mlds = (float*)(smem + 51200);

    const int t    = threadIdx.x;
    const int wave = t >> 6;
    const int lane = t & 63;
    const int l15  = lane & 15;
    const int quad = lane >> 4;

    const int bh = blockIdx.x & 31;       // all q-tiles of one head on one XCD
    const int qt = blockIdx.x >> 5;       // 0..15
    const int b  = bh >> 4;
    const int hh = bh & 15;
    const int q0 = qt * 128;              // 128 q rows per block

    const size_t headoff = (size_t)(b * NH + hh) * SEQ * HD;
    const u16* kbase = kb + headoff;
    const u16* vbase = vtb + (size_t)(hh * HD) * VSTR + b * SEQ;
    const float* m2b = m2g + b * SEQ;

    // stage mask2 row (2048 f32 = 8 KB) into LDS once; 512 threads x 1 float4
    ((float4*)mlds)[t] = ((const float4*)m2b)[t];

    bf16x8 Qf[2];
    {
        const int qrow = q0 + wave * 16 + l15;
#pragma unroll
        for (int ks = 0; ks < 2; ks++)
            Qf[ks] = *(const bf16x8*)(qb + headoff + (size_t)qrow * HD + ks * 32 + quad * 8);
    }

    f32x4 O[4];
#pragma unroll
    for (int mt = 0; mt < 4; mt++) O[mt] = (f32x4)0.0f;
    f32x4 Lacc = (f32x4)0.0f;             // lsum via MFMA (all rows identical)
    bf16x8 ones;
#pragma unroll
    for (int j = 0; j < 8; j++) ones[j] = (short)0x3F80;   // bf16 1.0

    const int srow = lane >> 3;
    const int lcol = (lane & 7) ^ srow;       // XOR-swizzled staging chunk
    const int sw0 = ((quad)     ^ (l15 & 7)) * 8;
    const int sw1 = ((quad + 4) ^ (l15 & 7)) * 8;

    // wave w stages K rows [w*8,w*8+8) and V' d-rows [w*8,w*8+8) of each tile
    const u16* kp = kbase + (size_t)(wave * 8 + srow) * HD + lcol * 8;
    const u16* vp = vbase + (size_t)(wave * 8 + srow) * VSTR + lcol * 8;

    // stage tile 0 into buffer 0
    ldsload16(kp, smem + wave * 1024);
    ldsload16(vp, smem + 16384 + wave * 1024);

    for (int i = 0; i < 32; i++) {
        __syncthreads();   // drains tile-i loads; tile i-1 compute finished
        const int c0 = i * 64;
        const u16* Ks  = (const u16*)(smem + (i & 1) * 8192);
        const u16* Vts = (const u16*)(smem + 16384 + (i & 1) * 8192);
        if (i + 1 < 32) {
            const int cn = c0 + 64;
            char* nbK = smem + ((i + 1) & 1) * 8192;
            char* nbV = smem + 16384 + ((i + 1) & 1) * 8192;
            ldsload16(kp + (size_t)cn * HD, nbK + wave * 1024);
            ldsload16(vp + cn,              nbV + wave * 1024);
        }

        // S^T: D[m=kv][n=q] = sum_d K[kv][d] * Q[q][d]
        f32x4 St[4];
        __builtin_amdgcn_s_setprio(1);
#pragma unroll
        for (int mt = 0; mt < 4; mt++) {
            const int rb = (mt * 16 + l15) * 64;
            const bf16x8 ka0 = *(const bf16x8*)&Ks[rb + sw0];
            const bf16x8 ka1 = *(const bf16x8*)&Ks[rb + sw1];
            f32x4 a = (f32x4)0.0f;
            a = mfma16(ka0, Qf[0], a);
            a = mfma16(ka1, Qf[1], a);
            St[mt] = a;
        }
        __builtin_amdgcn_s_setprio(0);

        // p = exp2(score*C2 + mask2); packed bf16 P (lsum via MFMA below)
#pragma unroll
        for (int mt = 0; mt < 4; mt++) {
            const f32x4 mv = *(const f32x4*)(mlds + c0 + mt * 16 + quad * 4);
            float p0 = __builtin_amdgcn_exp2f(fmaf(St[mt][0], C2, mv[0]));
            float p1 = __builtin_amdgcn_exp2f(fmaf(St[mt][1], C2, mv[1]));
            float p2 = __builtin_amdgcn_exp2f(fmaf(St[mt][2], C2, mv[2]));
            float p3 = __builtin_amdgcn_exp2f(fmaf(St[mt][3], C2, mv[3]));
            uint2 w;
            w.x = pk_bf16(p0, p1);
            w.y = pk_bf16(p2, p3);
            *(uint2*)&Pw[l15][mt * 16 + quad * 4] = w;
        }

        const bf16x8 Pb0 = *(const bf16x8*)&Pw[l15][quad * 8];
        const bf16x8 Pb1 = *(const bf16x8*)&Pw[l15][32 + quad * 8];

        // O^T: D[m=d][n=q] += sum_kv V[kv][d] * P[q][kv]; Lacc += sum_kv P
        __builtin_amdgcn_s_setprio(1);
#pragma unroll
        for (int mt = 0; mt < 4; mt++) {
            const int rb = (mt * 16 + l15) * 64;
            const bf16x8 va0 = *(const bf16x8*)&Vts[rb + sw0];
            const bf16x8 va1 = *(const bf16x8*)&Vts[rb + sw1];
            O[mt] = mfma16(va0, Pb0, O[mt]);
            O[mt] = mfma16(va1, Pb1, O[mt]);
        }
        Lacc = mfma16(ones, Pb0, Lacc);
        Lacc = mfma16(ones, Pb1, Lacc);
        __builtin_amdgcn_s_setprio(0);
    }

    const float linv = 1.0f / Lacc[0];    // per-q (col=l15) denominator, all lanes

    __syncthreads();
    float* Ot = (float*)smem + wave * (16 * 68);
#pragma unroll
    for (int mt = 0; mt < 4; mt++) {
        f32x4 v = O[mt] * linv;
        *(f32x4*)(Ot + l15 * 68 + mt * 16 + quad * 4) = v;
    }
    __syncthreads();
    {
        const int ql  = lane >> 2;
        const int seg = lane & 3;
        const float* srcp = Ot + ql * 68 + seg * 16;
        u16* dstp = ctx + (size_t)(b * SEQ + q0 + wave * 16 + ql) * HID
                        + hh * 64 + seg * 16;
#pragma unroll
        for (int j = 0; j < 2; j++) {
            union { u16 s[8]; uint4 v; } p;
#pragma unroll
            for (int i = 0; i < 8; i++) p.s[i] = f2bf(srcp[j * 8 + i]);
            *(uint4*)(dstp + j * 8) = p.v;
        }
    }
}

// ---------------------------------------------------------------------------
extern "C" void kernel_launch(void* const* d_in, const int* in_sizes, int n_in,
                              void* d_out, int out_size, void* d_ws, size_t ws_size,
                              hipStream_t stream)
{
    const float* hs    = (const float*)d_in[0];
    const float* mask  = (const float*)d_in[1];
    const float* Wq    = (const float*)d_in[2];
    const float* bq    = (const float*)d_in[3];
    const float* Wk    = (const float*)d_in[4];
    const float* bk    = (const float*)d_in[5];
    const float* Wv    = (const float*)d_in[6];
    const float* bv    = (const float*)d_in[7];
    const float* Wd    = (const float*)d_in[8];
    const float* bd    = (const float*)d_in[9];
    const float* gamma = (const float*)d_in[10];
    const float* beta  = (const float*)d_in[11];
    float* out = (float*)d_out;

    const size_t NE = (size_t)MROWS * HID;
    u16* ws   = (u16*)d_ws;
    u16* h    = ws;                          // bf16 [MROWS][HID]
    u16* qbb  = ws + NE;                     // bf16 [B,NH,S,HD]
    u16* kbb  = qbb + NE;                    // bf16 [B,NH,S,HD]
    u16* vtb  = kbb + NE;                    // bf16 [HID][VSTR]
    u16* ctxb = vtb + (size_t)HID * VSTR;    // bf16 [MROWS][HID]
    u16* wqb  = ctxb + NE;
    u16* wkb  = wqb + HID * HID;
    u16* wvb  = wkb + HID * HID;
    u16* wdb  = wvb + HID * HID;
    float* m2 = (float*)(wdb + HID * HID);   // fp32 [MROWS] precomputed mask2

    prep_kernel<<<8196, 256, 0, stream>>>(hs, gamma, beta, h,
                                          Wq, Wk, Wv, Wd, wqb, wkb, wvb, wdb,
                                          mask, m2);

    qkv_gemm<<<768, 256, 0, stream>>>(h, wqb, wkb, wvb, bq, bk, bv, qbb, kbb, vtb);

    attn_mfma<<<512, 512, 0, stream>>>(qbb, kbb, vtb, m2, ctxb);

    out_gemm<<<512, 256, 0, stream>>>(ctxb, wdb, bd, out);
}

// Round 10
// 195.089 us; speedup vs baseline: 1.0774x; 1.0201x over previous
//
#include <hip/hip_runtime.h>
#include <hip/hip_bf16.h>
#include <math.h>

#define BATCH 2
#define SEQ   2048
#define HID   1024
#define NH    16
#define HD    64
#define MROWS (BATCH * SEQ)   // 4096
#define VSTR  4160            // padded row stride of V' (avoid 8192B channel camping)

typedef unsigned short u16;
typedef short bf16x8 __attribute__((ext_vector_type(8)));
typedef float f32x4  __attribute__((ext_vector_type(4)));

#define LOG2E 1.4426950408889634f
#define C2    (0.125f * LOG2E)      // score scale folded into log2 domain
#define M2F   23.083120f            // fixed softmax shift (shift-invariant)

static __device__ __forceinline__ u16 f2bf(float f) {
    union { float f; unsigned int u; } v; v.f = f;
    unsigned int r = (v.u + 0x7FFF + ((v.u >> 16) & 1)) >> 16;  // RNE
    return (u16)r;
}

static __device__ __forceinline__ unsigned int pk_bf16(float a, float b) {
    union { __hip_bfloat162 h; unsigned int u; } r;
    float2 f; f.x = a; f.y = b;
    r.h = __float22bfloat162_rn(f);   // packed cvt where HW supports it
    return r.u;
}

static __device__ __forceinline__ f32x4 mfma16(bf16x8 a, bf16x8 b, f32x4 c) {
    return __builtin_amdgcn_mfma_f32_16x16x32_bf16(a, b, c, 0, 0, 0);
}

// global -> LDS async copy, 16 B per lane; LDS dest = wave-uniform base + lane*16.
static __device__ __forceinline__ void ldsload16(const void* g, void* l) {
    __builtin_amdgcn_global_load_lds(
        (const __attribute__((address_space(1))) void*)(unsigned long long)(uintptr_t)g,
        (__attribute__((address_space(3))) void*)(unsigned int)(uintptr_t)l,
        16, 0, 0);
}

// ---------------------------------------------------------------------------
// Fused prep: [0,4096) weight cast; [4096,8192) LayerNorm; [8192,8196) mask2
// precompute: mask2[s] = -1000*(1-mask)*LOG2E - M2F.
// ---------------------------------------------------------------------------
__global__ __launch_bounds__(256) void prep_kernel(const float* __restrict__ x,
                                                   const float* __restrict__ gamma,
                                                   const float* __restrict__ beta,
                                                   u16* __restrict__ h,
                                                   const float* __restrict__ w0,
                                                   const float* __restrict__ w1,
                                                   const float* __restrict__ w2,
                                                   const float* __restrict__ w3,
                                                   u16* o0, u16* o1, u16* o2, u16* o3,
                                                   const float* __restrict__ maskg,
                                                   float* __restrict__ m2g)
{
    __shared__ float red[8];
    const int t = threadIdx.x;
    if (blockIdx.x >= 8192) {
        const int idx = ((blockIdx.x - 8192) * 256 + t) * 4;
        const float4 m = *(const float4*)(maskg + idx);
        float4 o;
        o.x = fmaf(-1000.0f * (1.0f - m.x), LOG2E, -M2F);
        o.y = fmaf(-1000.0f * (1.0f - m.y), LOG2E, -M2F);
        o.z = fmaf(-1000.0f * (1.0f - m.z), LOG2E, -M2F);
        o.w = fmaf(-1000.0f * (1.0f - m.w), LOG2E, -M2F);
        *(float4*)(m2g + idx) = o;
        return;
    }
    if (blockIdx.x < 4096) {
        const int blk = blockIdx.x;
        const int which = blk >> 10;
        const int lb = blk & 1023;
        const float* src = which == 0 ? w0 : which == 1 ? w1 : which == 2 ? w2 : w3;
        u16* dst = which == 0 ? o0 : which == 1 ? o1 : which == 2 ? o2 : o3;
        const int idx = (lb * 256 + t) * 4;
        const float4 f = *(const float4*)(src + idx);
        union { u16 s[4]; uint2 v; } p;
        p.s[0] = f2bf(f.x); p.s[1] = f2bf(f.y); p.s[2] = f2bf(f.z); p.s[3] = f2bf(f.w);
        *(uint2*)(dst + idx) = p.v;
        return;
    }
    const int row = blockIdx.x - 4096;
    const float4 xv = ((const float4*)(x + (size_t)row * HID))[t];
    float s  = xv.x + xv.y + xv.z + xv.w;
    float ss = xv.x * xv.x + xv.y * xv.y + xv.z * xv.z + xv.w * xv.w;
#pragma unroll
    for (int off = 32; off > 0; off >>= 1) {
        s  += __shfl_down(s, off);
        ss += __shfl_down(ss, off);
    }
    const int wid = t >> 6;
    if ((t & 63) == 0) { red[wid] = s; red[4 + wid] = ss; }
    __syncthreads();
    s  = red[0] + red[1] + red[2] + red[3];
    ss = red[4] + red[5] + red[6] + red[7];
    const float mu   = s * (1.0f / HID);
    const float var  = ss * (1.0f / HID) - mu * mu;
    const float rstd = rsqrtf(var + 1e-12f);
    const float4 g  = ((const float4*)gamma)[t];
    const float4 bb = ((const float4*)beta)[t];
    union { u16 s[4]; uint2 v; } p;
    p.s[0] = f2bf((xv.x - mu) * rstd * g.x + bb.x);
    p.s[1] = f2bf((xv.y - mu) * rstd * g.y + bb.y);
    p.s[2] = f2bf((xv.z - mu) * rstd * g.z + bb.z);
    p.s[3] = f2bf((xv.w - mu) * rstd * g.w + bb.w);
    ((uint2*)(h + (size_t)row * HID))[t] = p.v;
}

// ---------------------------------------------------------------------------
// MFMA GEMM core v3: 128x128 tile, BK=32, EIGHT waves (2M x 4N, wave=64x32),
// double-buffered.  Same tile/LDS/barrier structure as the 4-wave core, but
// 512 threads -> 768 blocks x 8 waves = 24 waves/CU (6/SIMD, was 3/SIMD):
// doubles the latency-hiding pool across the per-K-step vmcnt-drain+barrier.
// Per thread per K-step: 1 A-load + 1 B-load (16 B each).
// A[M,K], B[N,K] row-major bf16 (C = A * B^T).  As/Bs are 8192-u16 (2 bufs).
// ---------------------------------------------------------------------------
static __device__ __forceinline__ void gemm_core8w(const u16* __restrict__ A,
                                                   const u16* __restrict__ B,
                                                   int K, int bm, int bn,
                                                   u16* As, u16* Bs,
                                                   int tid,
                                                   f32x4 acc[4][2])
{
    const int lane = tid & 63;
    const int wave = tid >> 6;
    const int l15  = lane & 15;
    const int quad = lane >> 4;
    const int wm = (wave >> 2) * 64;      // 2 M-groups
    const int wn = (wave & 3) * 32;       // 4 N-groups

    const u16* A1 = A + (size_t)(bm + (tid >> 2)) * K + (tid & 3) * 8;
    const u16* B1 = B + (size_t)(bn + (tid >> 2)) * K + (tid & 3) * 8;
    const int o = wave * 512;             // wave's staging chunk (u16 units)

    // stage K-step 0 into buffer 0
    ldsload16(A1, As + o);
    ldsload16(B1, Bs + o);

    const int nstep = K >> 5;
    for (int i = 0; i < nstep; i++) {
        __syncthreads();                  // drains step-i loads (vmcnt 0)
        const int cb = (i & 1) * 4096;
        if (i + 1 < nstep) {
            const int nb = ((i + 1) & 1) * 4096;
            const int k0 = (i + 1) * 32;
            ldsload16(A1 + k0, As + nb + o);
            ldsload16(B1 + k0, Bs + nb + o);
        }
        bf16x8 af[4], bfr[2];
#pragma unroll
        for (int mt = 0; mt < 4; mt++)
            af[mt] = *(const bf16x8*)&As[cb + (wm + mt * 16 + l15) * 32 + quad * 8];
#pragma unroll
        for (int nt = 0; nt < 2; nt++)
            bfr[nt] = *(const bf16x8*)&Bs[cb + (wn + nt * 16 + l15) * 32 + quad * 8];
#pragma unroll
        for (int mt = 0; mt < 4; mt++)
#pragma unroll
            for (int nt = 0; nt < 2; nt++)
                acc[mt][nt] = mfma16(af[mt], bfr[nt], acc[mt][nt]);
    }
}

// ---------------------------------------------------------------------------
// Fused QKV, 128x128 tiles, 8 waves/block, XCD-chunked swizzle (round-9 map).
// Logical blocks 0..511: q/k interleaved pairs sharing (bm,bn) A-panel.
// Logical 512..767: V' = Wv*h^T, bm-fastest for h-panel L2 reuse.
// ---------------------------------------------------------------------------
__global__ __launch_bounds__(512, 6) void qkv_gemm(const u16* __restrict__ h,
                                                   const u16* __restrict__ wq,
                                                   const u16* __restrict__ wk,
                                                   const u16* __restrict__ wv,
                                                   const float* __restrict__ bq,
                                                   const float* __restrict__ bk,
                                                   const float* __restrict__ bv,
                                                   u16* __restrict__ qo,
                                                   u16* __restrict__ ko,
                                                   u16* __restrict__ vo)
{
    __shared__ u16 As[8192];
    __shared__ u16 Bs[8192];
    // bijective chunked XCD swizzle (768 % 8 == 0)
    const int blk  = (blockIdx.x & 7) * 96 + (blockIdx.x >> 3);
    const int tid  = threadIdx.x;
    const int wave = tid >> 6;
    const int lane = tid & 63;
    const int l15  = lane & 15;
    const int quad = lane >> 4;
    const int wm = (wave >> 2) * 64;
    const int wn = (wave & 3) * 32;

    f32x4 acc[4][2];
#pragma unroll
    for (int mt = 0; mt < 4; mt++)
#pragma unroll
        for (int nt = 0; nt < 2; nt++) acc[mt][nt] = (f32x4)0.0f;

    if (blk < 512) {
        const int proj  = blk & 1;            // 0=q, 1=k (pairs share A panel)
        const int pair  = blk >> 1;           // 0..255
        const u16* W     = proj ? wk : wq;
        const float* bia = proj ? bk : bq;
        u16* out         = proj ? ko : qo;
        const int bm = (pair >> 3) * 128;     // 32 M-tiles
        const int bn = (pair & 7) * 128;      // 8 N-tiles
        gemm_core8w(h, W, HID, bm, bn, As, Bs, tid, acc);

        float bv2[2];
#pragma unroll
        for (int nt = 0; nt < 2; nt++) bv2[nt] = bia[bn + wn + nt * 16 + l15];
#pragma unroll
        for (int mt = 0; mt < 4; mt++)
#pragma unroll
            for (int r = 0; r < 4; r++) {
                const int m  = bm + wm + mt * 16 + quad * 4 + r;
                const int bI = m >> 11;
                const int sI = m & (SEQ - 1);
#pragma unroll
                for (int nt = 0; nt < 2; nt++) {
                    const int n  = bn + wn + nt * 16 + l15;
                    const int hh = n >> 6;
                    const int d  = n & 63;
                    out[(((size_t)(bI * NH + hh) * SEQ + sI) << 6) + d] =
                        f2bf(acc[mt][nt][r] + bv2[nt]);
                }
            }
    } else {
        const int local = blk - 512;          // 0..255
        const int bm = (local & 7) * 128;     // bm-fastest: 8 tiles over Wv rows
        const int bn = (local >> 3) * 128;    // 32 tiles over h rows
        gemm_core8w(wv, h, HID, bm, bn, As, Bs, tid, acc);

#pragma unroll
        for (int mt = 0; mt < 4; mt++) {
            const f32x4 bm4 = *(const f32x4*)&bv[bm + wm + mt * 16 + quad * 4];
#pragma unroll
            for (int r = 0; r < 4; r++) {
                const int row = bm + wm + mt * 16 + quad * 4 + r;
#pragma unroll
                for (int nt = 0; nt < 2; nt++) {
                    const int col = bn + wn + nt * 16 + l15;
                    vo[(size_t)row * VSTR + col] = f2bf(acc[mt][nt][r] + bm4[r]);
                }
            }
        }
    }
}

// ---------------------------------------------------------------------------
// MFMA GEMM core v2: 128x64 tile, BK=32, 4 waves 2x2 (wave = 64x32), dbuf.
// As = 8192 u16 (2 x 128x32), Bs = 4096 u16 (2 x 64x32).  LDS 24 KB.
// ---------------------------------------------------------------------------
static __device__ __forceinline__ void gemm_core64(const u16* __restrict__ A,
                                                   const u16* __restrict__ B,
                                                   int K, int bm, int bn,
                                                   u16* As, u16* Bs,
                                                   int wave, int lane,
                                                   f32x4 acc[4][2])
{
    const int l15  = lane & 15;
    const int quad = lane >> 4;
    const int wm = (wave >> 1) * 64;
    const int wn = (wave & 1) * 32;

    const int c1 = wave * 64 + lane;      // 0..255
    const int c2 = c1 + 256;
    const u16* A1 = A + (size_t)(bm + (c1 >> 2)) * K + (c1 & 3) * 8;
    const u16* A2 = A + (size_t)(bm + (c2 >> 2)) * K + (c2 & 3) * 8;
    const u16* B1 = B + (size_t)(bn + (c1 >> 2)) * K + (c1 & 3) * 8;
    const int o1 = wave * 512;            // A rows wave*16..+16
    const int o2 = 2048 + wave * 512;     // A rows 64+wave*16..+16
    const int ob = wave * 512;            // B rows wave*16..+16

    // stage K-step 0 into buffer 0
    ldsload16(A1, As + o1);
    ldsload16(A2, As + o2);
    ldsload16(B1, Bs + ob);

    const int nstep = K >> 5;
    for (int i = 0; i < nstep; i++) {
        __syncthreads();                  // drains step-i loads (vmcnt 0)
        const int ca = (i & 1) * 4096;
        const int cbb = (i & 1) * 2048;
        if (i + 1 < nstep) {
            const int na = ((i + 1) & 1) * 4096;
            const int nb = ((i + 1) & 1) * 2048;
            const int k0 = (i + 1) * 32;
            ldsload16(A1 + k0, As + na + o1);
            ldsload16(A2 + k0, As + na + o2);
            ldsload16(B1 + k0, Bs + nb + ob);
        }
        bf16x8 af[4], bfr[2];
#pragma unroll
        for (int mt = 0; mt < 4; mt++)
            af[mt] = *(const bf16x8*)&As[ca + (wm + mt * 16 + l15) * 32 + quad * 8];
#pragma unroll
        for (int nt = 0; nt < 2; nt++)
            bfr[nt] = *(const bf16x8*)&Bs[cbb + (wn + nt * 16 + l15) * 32 + quad * 8];
#pragma unroll
        for (int mt = 0; mt < 4; mt++)
#pragma unroll
            for (int nt = 0; nt < 2; nt++)
                acc[mt][nt] = mfma16(af[mt], bfr[nt], acc[mt][nt]);
    }
}

// ---------------------------------------------------------------------------
// Output projection, 128x64 tiles + XCD-chunked swizzle, bn-fastest:
// chunk of 64 = 4 A(ctx) panels (1 MB) + full wd (2 MB) -> L2-resident.
// ---------------------------------------------------------------------------
__global__ __launch_bounds__(256, 6) void out_gemm(const u16* __restrict__ ctx,
                                                   const u16* __restrict__ wd,
                                                   const float* __restrict__ bd,
                                                   float* __restrict__ out)
{
    __shared__ u16 As[8192];
    __shared__ u16 Bs[4096];
    const int blk  = (blockIdx.x & 7) * 64 + (blockIdx.x >> 3);  // 512 % 8 == 0
    const int wave = threadIdx.x >> 6;
    const int lane = threadIdx.x & 63;
    const int l15  = lane & 15;
    const int quad = lane >> 4;
    const int wm = (wave >> 1) * 64;
    const int wn = (wave & 1) * 32;
    const int bm = (blk >> 4) * 128;      // 32 M-tiles
    const int bn = (blk & 15) * 64;       // 16 N-tiles, fastest

    f32x4 acc[4][2];
#pragma unroll
    for (int mt = 0; mt < 4; mt++)
#pragma unroll
        for (int nt = 0; nt < 2; nt++) acc[mt][nt] = (f32x4)0.0f;

    gemm_core64(ctx, wd, HID, bm, bn, As, Bs, wave, lane, acc);

    float bv2[2];
#pragma unroll
    for (int nt = 0; nt < 2; nt++) bv2[nt] = bd[bn + wn + nt * 16 + l15];
#pragma unroll
    for (int mt = 0; mt < 4; mt++)
#pragma unroll
        for (int r = 0; r < 4; r++) {
            const int m = bm + wm + mt * 16 + quad * 4 + r;
#pragma unroll
            for (int nt = 0; nt < 2; nt++) {
                const int n = bn + wn + nt * 16 + l15;
                out[(size_t)m * HID + n] = acc[mt][nt][r] + bv2[nt];
            }
        }
}

// ---------------------------------------------------------------------------
// MFMA flash attention (v5, measured 56.5-57us): 8-wave blocks (128 q rows),
// K/V double buffer shared by all waves, mask2 staged in LDS once, lsum via
// MFMA with all-ones A fragment.  LDS: K @0,8192 | V @16384,24576 | P @32768
// (8x2304) | mask @51200 (8 KB) = 59392.  Grid 512 = 2 blocks/CU.
// ---------------------------------------------------------------------------
__global__ __launch_bounds__(512, 4) void attn_mfma(const u16* __restrict__ qb,
                                                    const u16* __restrict__ kb,
                                                    const u16* __restrict__ vtb,
                                                    const float* __restrict__ m2g,
                                                    u16* __restrict__ ctx)
{
    __shared__ __align__(16) char smem[59392];
    u16 (*Pw)[72] = (u16(*)[72])(smem + 32768 + (threadIdx.x >> 6) * 2304);
    float* mlds = (float*)(smem + 51200);

    const int t    = threadIdx.x;
    const int wave = t >> 6;
    const int lane = t & 63;
    const int l15  = lane & 15;
    const int quad = lane >> 4;

    const int bh = blockIdx.x & 31;       // all q-tiles of one head on one XCD
    const int qt = blockIdx.x >> 5;       // 0..15
    const int b  = bh >> 4;
    const int hh = bh & 15;
    const int q0 = qt * 128;              // 128 q rows per block

    const size_t headoff = (size_t)(b * NH + hh) * SEQ * HD;
    const u16* kbase = kb + headoff;
    const u16* vbase = vtb + (size_t)(hh * HD) * VSTR + b * SEQ;
    const float* m2b = m2g + b * SEQ;

    // stage mask2 row (2048 f32 = 8 KB) into LDS once; 512 threads x 1 float4
    ((float4*)mlds)[t] = ((const float4*)m2b)[t];

    bf16x8 Qf[2];
    {
        const int qrow = q0 + wave * 16 + l15;
#pragma unroll
        for (int ks = 0; ks < 2; ks++)
            Qf[ks] = *(const bf16x8*)(qb + headoff + (size_t)qrow * HD + ks * 32 + quad * 8);
    }

    f32x4 O[4];
#pragma unroll
    for (int mt = 0; mt < 4; mt++) O[mt] = (f32x4)0.0f;
    f32x4 Lacc = (f32x4)0.0f;             // lsum via MFMA (all rows identical)
    bf16x8 ones;
#pragma unroll
    for (int j = 0; j < 8; j++) ones[j] = (short)0x3F80;   // bf16 1.0

    const int srow = lane >> 3;
    const int lcol = (lane & 7) ^ srow;       // XOR-swizzled staging chunk
    const int sw0 = ((quad)     ^ (l15 & 7)) * 8;
    const int sw1 = ((quad + 4) ^ (l15 & 7)) * 8;

    // wave w stages K rows [w*8,w*8+8) and V' d-rows [w*8,w*8+8) of each tile
    const u16* kp = kbase + (size_t)(wave * 8 + srow) * HD + lcol * 8;
    const u16* vp = vbase + (size_t)(wave * 8 + srow) * VSTR + lcol * 8;

    // stage tile 0 into buffer 0
    ldsload16(kp, smem + wave * 1024);
    ldsload16(vp, smem + 16384 + wave * 1024);

    for (int i = 0; i < 32; i++) {
        __syncthreads();   // drains tile-i loads; tile i-1 compute finished
        const int c0 = i * 64;
        const u16* Ks  = (const u16*)(smem + (i & 1) * 8192);
        const u16* Vts = (const u16*)(smem + 16384 + (i & 1) * 8192);
        if (i + 1 < 32) {
            const int cn = c0 + 64;
            char* nbK = smem + ((i + 1) & 1) * 8192;
            char* nbV = smem + 16384 + ((i + 1) & 1) * 8192;
            ldsload16(kp + (size_t)cn * HD, nbK + wave * 1024);
            ldsload16(vp + cn,              nbV + wave * 1024);
        }

        // S^T: D[m=kv][n=q] = sum_d K[kv][d] * Q[q][d]
        f32x4 St[4];
        __builtin_amdgcn_s_setprio(1);
#pragma unroll
        for (int mt = 0; mt < 4; mt++) {
            const int rb = (mt * 16 + l15) * 64;
            const bf16x8 ka0 = *(const bf16x8*)&Ks[rb + sw0];
            const bf16x8 ka1 = *(const bf16x8*)&Ks[rb + sw1];
            f32x4 a = (f32x4)0.0f;
            a = mfma16(ka0, Qf[0], a);
            a = mfma16(ka1, Qf[1], a);
            St[mt] = a;
        }
        __builtin_amdgcn_s_setprio(0);

        // p = exp2(score*C2 + mask2); packed bf16 P (lsum via MFMA below)
#pragma unroll
        for (int mt = 0; mt < 4; mt++) {
            const f32x4 mv = *(const f32x4*)(mlds + c0 + mt * 16 + quad * 4);
            float p0 = __builtin_amdgcn_exp2f(fmaf(St[mt][0], C2, mv[0]));
            float p1 = __builtin_amdgcn_exp2f(fmaf(St[mt][1], C2, mv[1]));
            float p2 = __builtin_amdgcn_exp2f(fmaf(St[mt][2], C2, mv[2]));
            float p3 = __builtin_amdgcn_exp2f(fmaf(St[mt][3], C2, mv[3]));
            uint2 w;
            w.x = pk_bf16(p0, p1);
            w.y = pk_bf16(p2, p3);
            *(uint2*)&Pw[l15][mt * 16 + quad * 4] = w;
        }

        const bf16x8 Pb0 = *(const bf16x8*)&Pw[l15][quad * 8];
        const bf16x8 Pb1 = *(const bf16x8*)&Pw[l15][32 + quad * 8];

        // O^T: D[m=d][n=q] += sum_kv V[kv][d] * P[q][kv]; Lacc += sum_kv P
        __builtin_amdgcn_s_setprio(1);
#pragma unroll
        for (int mt = 0; mt < 4; mt++) {
            const int rb = (mt * 16 + l15) * 64;
            const bf16x8 va0 = *(const bf16x8*)&Vts[rb + sw0];
            const bf16x8 va1 = *(const bf16x8*)&Vts[rb + sw1];
            O[mt] = mfma16(va0, Pb0, O[mt]);
            O[mt] = mfma16(va1, Pb1, O[mt]);
        }
        Lacc = mfma16(ones, Pb0, Lacc);
        Lacc = mfma16(ones, Pb1, Lacc);
        __builtin_amdgcn_s_setprio(0);
    }

    const float linv = 1.0f / Lacc[0];    // per-q (col=l15) denominator, all lanes

    __syncthreads();
    float* Ot = (float*)smem + wave * (16 * 68);
#pragma unroll
    for (int mt = 0; mt < 4; mt++) {
        f32x4 v = O[mt] * linv;
        *(f32x4*)(Ot + l15 * 68 + mt * 16 + quad * 4) = v;
    }
    __syncthreads();
    {
        const int ql  = lane >> 2;
        const int seg = lane & 3;
        const float* srcp = Ot + ql * 68 + seg * 16;
        u16* dstp = ctx + (size_t)(b * SEQ + q0 + wave * 16 + ql) * HID
                        + hh * 64 + seg * 16;
#pragma unroll
        for (int j = 0; j < 2; j++) {
            union { u16 s[8]; uint4 v; } p;
#pragma unroll
            for (int i = 0; i < 8; i++) p.s[i] = f2bf(srcp[j * 8 + i]);
            *(uint4*)(dstp + j * 8) = p.v;
        }
    }
}

// ---------------------------------------------------------------------------
extern "C" void kernel_launch(void* const* d_in, const int* in_sizes, int n_in,
                              void* d_out, int out_size, void* d_ws, size_t ws_size,
                              hipStream_t stream)
{
    const float* hs    = (const float*)d_in[0];
    const float* mask  = (const float*)d_in[1];
    const float* Wq    = (const float*)d_in[2];
    const float* bq    = (const float*)d_in[3];
    const float* Wk    = (const float*)d_in[4];
    const float* bk    = (const float*)d_in[5];
    const float* Wv    = (const float*)d_in[6];
    const float* bv    = (const float*)d_in[7];
    const float* Wd    = (const float*)d_in[8];
    const float* bd    = (const float*)d_in[9];
    const float* gamma = (const float*)d_in[10];
    const float* beta  = (const float*)d_in[11];
    float* out = (float*)d_out;

    const size_t NE = (size_t)MROWS * HID;
    u16* ws   = (u16*)d_ws;
    u16* h    = ws;                          // bf16 [MROWS][HID]
    u16* qbb  = ws + NE;                     // bf16 [B,NH,S,HD]
    u16* kbb  = qbb + NE;                    // bf16 [B,NH,S,HD]
    u16* vtb  = kbb + NE;                    // bf16 [HID][VSTR]
    u16* ctxb = vtb + (size_t)HID * VSTR;    // bf16 [MROWS][HID]
    u16* wqb  = ctxb + NE;
    u16* wkb  = wqb + HID * HID;
    u16* wvb  = wkb + HID * HID;
    u16* wdb  = wvb + HID * HID;
    float* m2 = (float*)(wdb + HID * HID);   // fp32 [MROWS] precomputed mask2

    prep_kernel<<<8196, 256, 0, stream>>>(hs, gamma, beta, h,
                                          Wq, Wk, Wv, Wd, wqb, wkb, wvb, wdb,
                                          mask, m2);

    qkv_gemm<<<768, 512, 0, stream>>>(h, wqb, wkb, wvb, bq, bk, bv, qbb, kbb, vtb);

    attn_mfma<<<512, 512, 0, stream>>>(qbb, kbb, vtb, m2, ctxb);

    out_gemm<<<512, 256, 0, stream>>>(ctxb, wdb, bd, out);
}